// Round 10
// baseline (36.957 us; speedup 1.0000x reference)
//
#include <hip/hip_runtime.h>
#include <math.h>

// ---------------------------------------------------------------------------
// HessianLoss — march + face-payload sharing, occupancy-tuned.
// R9 post-mortem: kernel is stall-bound (issue time ~3us vs ~22us runtime);
// payload live set (~160-180 VGPR) capped occupancy at 2 waves/SIMD. R10:
//   - __launch_bounds__(256,3): VGPR cap 170 -> 3 waves/SIMD (R4 showed a
//     4-wave cap spills this live set; 3 is the safe point)
//   - lifetime-ordered step: issue both shuffle batches early, cover their
//     latency with addc/mkface VALU, consume late; F1 dies mid-step
//   - slim carried/shuffled payloads: F4 = h+w (12), F5 = e+w (12)
// Face/role table (math identical to verified R6-R9):
//   F1=f1@(r,c) i0      F2=f2@(r,c) i0      F3=f1@(r,c-1) i1
//   F4=f1@(r-1,c-1) i2  F5=f2@(r-1,c-1) i1  F6=f2@(r-1,c) i2
// Lane 0 of each wave is a GHOST column (payload producer only).
// Degenerate/clamped faces give NaN payloads; all such uses are guarded.
// No __threadfence (R3-R5: L2 invalidate, +80us). No LDS staging (R3).
// ---------------------------------------------------------------------------

struct F15 { float e[3], h[3], w[9]; };   // e02, e10, aw = area*g
struct F12 { float h[3], w[9]; };         // role-i2 payload

__device__ __forceinline__ float3 d3(float3 t, float3 v)
{
    return make_float3(t.x - v.x, t.y - v.y, t.z - v.z);
}
__device__ __forceinline__ float3 shfl_dn3(float3 v)
{
    return make_float3(__shfl_down(v.x, 1, 64), __shfl_down(v.y, 1, 64),
                       __shfl_down(v.z, 1, 64));
}

__device__ __forceinline__ F15 mkface(float3 V0, float3 V1, float3 V2,
                                      float3 D0, float3 D1, float3 D2)
{
    float ax = V2.x - V1.x, ay = V2.y - V1.y, az = V2.z - V1.z;   // v21
    float bx = V0.x - V2.x, by = V0.y - V2.y, bz = V0.z - V2.z;   // v02
    float cx = V1.x - V0.x, cy = V1.y - V0.y, cz = V1.z - V0.z;   // v10
    float nx = ay * bz - az * by;
    float ny = az * bx - ax * bz;
    float nz = ax * by - ay * bx;
    float A2 = nx * nx + ny * ny + nz * nz;
    float invA2 = __builtin_amdgcn_rcpf(A2);
    float sc = 0.5f * __builtin_amdgcn_rsqf(A2);      // area / A2
    float e1x = ny * bz - nz * by, e1y = nz * bx - nx * bz, e1z = nx * by - ny * bx;
    float e2x = ny * cz - nz * cy, e2y = nz * cx - nx * cz, e2z = nx * cy - ny * cx;
    F15 f;
    f.e[0] = e1x * invA2; f.e[1] = e1y * invA2; f.e[2] = e1z * invA2;
    f.h[0] = e2x * invA2; f.h[1] = e2y * invA2; f.h[2] = e2z * invA2;
    float s1x = e1x * sc, s1y = e1y * sc, s1z = e1z * sc;         // area*e02
    float s2x = e2x * sc, s2y = e2y * sc, s2z = e2z * sc;         // area*e10
    float d1x = D1.x - D0.x, d1y = D1.y - D0.y, d1z = D1.z - D0.z;
    float d2x = D2.x - D0.x, d2y = D2.y - D0.y, d2z = D2.z - D0.z;
    f.w[0] = s1x * d1x + s2x * d2x;
    f.w[1] = s1x * d1y + s2x * d2y;
    f.w[2] = s1x * d1z + s2x * d2z;
    f.w[3] = s1y * d1x + s2y * d2x;
    f.w[4] = s1y * d1y + s2y * d2y;
    f.w[5] = s1y * d1z + s2y * d2z;
    f.w[6] = s1z * d1x + s2z * d2x;
    f.w[7] = s1z * d1y + s2z * d2y;
    f.w[8] = s1z * d1z + s2z * d2z;
    return f;
}

// acc += K (x) w-rows over the 6 weighted pairs
__device__ __forceinline__ void addKW(const float K0, const float K1, const float K2,
                                      const float w[9], float acc[6][3])
{
    const float K[3] = {K0, K1, K2};
    const int pa[6] = {0, 1, 2, 0, 0, 1};
    const int pb[6] = {0, 1, 2, 1, 2, 2};
#pragma unroll
    for (int p = 0; p < 6; ++p)
#pragma unroll
        for (int cc = 0; cc < 3; ++cc)
            acc[p][cc] += K[pa[p]] * w[pb[p] * 3 + cc];
}

__device__ __forceinline__ void addc0(const F15& f, float acc[6][3])
{
    addKW(-(f.e[0] + f.h[0]), -(f.e[1] + f.h[1]), -(f.e[2] + f.h[2]), f.w, acc);
}

__device__ __forceinline__ F15 shfl_up_f15(const F15& f)
{
    F15 r;
#pragma unroll
    for (int i = 0; i < 3; ++i) {
        r.e[i] = __shfl_up(f.e[i], 1, 64);
        r.h[i] = __shfl_up(f.h[i], 1, 64);
    }
#pragma unroll
    for (int i = 0; i < 9; ++i) r.w[i] = __shfl_up(f.w[i], 1, 64);
    return r;
}

__device__ __forceinline__ float sq_acc(const float acc[6][3])
{
    float s1 = 0.0f, s2 = 0.0f;
#pragma unroll
    for (int p = 0; p < 3; ++p)
#pragma unroll
        for (int cc = 0; cc < 3; ++cc) s1 += acc[p][cc] * acc[p][cc];
#pragma unroll
    for (int p = 3; p < 6; ++p)
#pragma unroll
        for (int cc = 0; cc < 3; ++cc) s2 += acc[p][cc] * acc[p][cc];
    return s1 + 2.0f * s2;
}

#define MK 4             // rows marched per thread
#define OUTW 63          // output columns per wave (lane 0 = ghost)
#define BOUT (4 * OUTW)  // 252 output columns per 256-thread block

__global__ __launch_bounds__(256, 3)
void hess_face2(const float* __restrict__ vsf, const float* __restrict__ vtf,
                float* __restrict__ partials, int W, int H)
{
    const float3* vs = (const float3*)vsf;
    const float3* vt = (const float3*)vtf;
    const int tid = threadIdx.x, lane = tid & 63, wvid = tid >> 6;
    const int c = blockIdx.x * BOUT + wvid * OUTW + lane - 1;
    const int r0 = blockIdx.y * MK;
    const bool valid = (lane > 0) && (c < W);
    const bool cp = (c < W - 1), cm = (c > 0);
    const int cL = (c < 0) ? 0 : ((c > W - 1) ? W - 1 : c);
    const int cR = (c + 1 > W - 1) ? W - 1 : ((c + 1 < 0) ? 0 : c + 1);

    // ---- prologue: rows r0-1 (clamped), r0; build initial F4, F6 ----
    const int otop = (r0 > 0 ? r0 - 1 : 0) * W;
    const int obot = r0 * W;
    float3 V00 = vs[otop + cL];  float3 D00 = d3(vt[otop + cL], V00);
    float3 V10 = vs[obot + cL];  float3 D10 = d3(vt[obot + cL], V10);
    float3 V01 = shfl_dn3(V00),  D01 = shfl_dn3(D00);
    float3 V11 = shfl_dn3(V10),  D11 = shfl_dn3(D10);
    if (lane == 63) {
        float3 v = vs[otop + cR]; V01 = v; D01 = d3(vt[otop + cR], v);
        v = vs[obot + cR];        V11 = v; D11 = d3(vt[obot + cR], v);
    }
    F12 F4;
    {
        F15 F1p = mkface(V00, V01, V11, D00, D01, D11);   // f1@(r0-1,c)
#pragma unroll
        for (int i = 0; i < 3; ++i) F4.h[i] = __shfl_up(F1p.h[i], 1, 64);
#pragma unroll
        for (int i = 0; i < 9; ++i) F4.w[i] = __shfl_up(F1p.w[i], 1, 64);
    }
    F15 F6 = mkface(V00, V11, V10, D00, D11, D10);        // f2@(r0-1,c)

    // advance to rows r0, r0+1
    V00 = V10; D00 = D10; V01 = V11; D01 = D11;
    const int o1 = (r0 + 1 < H ? r0 + 1 : H - 1) * W;
    V10 = vs[o1 + cL]; D10 = d3(vt[o1 + cL], V10);
    V11 = shfl_dn3(V10); D11 = shfl_dn3(D10);
    if (lane == 63) {
        float3 v = vs[o1 + cR]; V11 = v; D11 = d3(vt[o1 + cR], v);
    }

    float s = 0.0f;
#pragma unroll
    for (int k = 0; k < MK; ++k) {
        const int r = r0 + k;
        const bool rp = (r < H - 1), rm = (r > 0);   // wave-uniform

        // prefetch row r+2 (own column; lane-63 also right column)
        float3 P = make_float3(0.f, 0.f, 0.f), TP = P, PR = P, TPR = P;
        if (k < MK - 1) {
            const int ob = (r + 2 < H ? r + 2 : H - 1) * W;
            P = vs[ob + cL]; TP = vt[ob + cL];
            if (lane == 63) { PR = vs[ob + cR]; TPR = vt[ob + cR]; }
        }

        // build own faces; issue both shuffle batches early, consume late
        F15 F1 = mkface(V00, V01, V11, D00, D01, D11);   // f1@(r,c)
        F15 F3 = shfl_up_f15(F1);                        // f1@(r,c-1)
        float F5e[3], F5w[9];                            // f2@(r-1,c-1): e+w of F6
#pragma unroll
        for (int i = 0; i < 3; ++i) F5e[i] = __shfl_up(F6.e[i], 1, 64);
#pragma unroll
        for (int i = 0; i < 9; ++i) F5w[i] = __shfl_up(F6.w[i], 1, 64);

        float acc[6][3] = {};
        if (rp && cp) addc0(F1, acc);                    // cover shuffle latency
        F15 F2 = mkface(V00, V11, V10, D00, D11, D10);   // f2@(r,c)
        if (rp && cp) addc0(F2, acc);
        if (rm && cp) addKW(F6.h[0], F6.h[1], F6.h[2], F6.w, acc);   // F6 i2
        if (rp && cm) addKW(F3.e[0], F3.e[1], F3.e[2], F3.w, acc);   // F3 i1
        if (rm && cm) {
            addKW(F5e[0], F5e[1], F5e[2], F5w, acc);                 // F5 i1
            addKW(F4.h[0], F4.h[1], F4.h[2], F4.w, acc);             // F4 i2
        }
        s += sq_acc(acc);

        // rotate
#pragma unroll
        for (int i = 0; i < 3; ++i) F4.h[i] = F3.h[i];
#pragma unroll
        for (int i = 0; i < 9; ++i) F4.w[i] = F3.w[i];
        F6 = F2;
        V00 = V10; D00 = D10; V01 = V11; D01 = D11;
        V10 = P;   D10 = d3(TP, P);
        V11 = shfl_dn3(V10); D11 = shfl_dn3(D10);
        if (lane == 63) { V11 = PR; D11 = d3(TPR, PR); }
    }

    if (!valid) s = 0.0f;   // overwrite: kills ghost/out-of-range NaN

    // ---- block reduce + plain partial store ----
#pragma unroll
    for (int o = 32; o > 0; o >>= 1) s += __shfl_down(s, o, 64);
    __shared__ float sm[4];
    if (lane == 0) sm[wvid] = s;
    __syncthreads();
    if (tid == 0)
        partials[blockIdx.y * gridDim.x + blockIdx.x] = sm[0] + sm[1] + sm[2] + sm[3];
}

// ------------- fallback: 1-D per-vertex gather (any grid dims) -------------

__global__ void hess_gather(const float* __restrict__ vsf, const float* __restrict__ vtf,
                            float* __restrict__ partials, int W, int H)
{
    const float3* vs = (const float3*)vsf;
    const float3* vt = (const float3*)vtf;
    int v = blockIdx.x * blockDim.x + threadIdx.x;
    int n = W * H;
    float s = 0.0f;
    if (v < n) {
        int r = v / W;
        int c = v - r * W;
        bool rp = (r < H - 1), rm = (r >= 1), cp = (c < W - 1), cm = (c >= 1);
        int i01 = cp ? v + 1 : v;
        int i11 = (rp && cp) ? v + W + 1 : v;
        int i10 = rp ? v + W : v;
        int im  = cm ? v - 1 : v;
        int idd = (rm && cm) ? v - W - 1 : v;
        int iu  = rm ? v - W : v;
        float3 P00 = vs[v],   D00 = d3(vt[v], P00);
        float3 P01 = vs[i01], D01 = d3(vt[i01], P01);
        float3 P11 = vs[i11], D11 = d3(vt[i11], P11);
        float3 P10 = vs[i10], D10 = d3(vt[i10], P10);
        float3 Pm  = vs[im],  Dm  = d3(vt[im], Pm);
        float3 Pdd = vs[idd], Ddd = d3(vt[idd], Pdd);
        float3 Pu  = vs[iu],  Du  = d3(vt[iu], Pu);
        float acc[6][3] = {};
        if (rp && cp) {
            addc0(mkface(P00, P01, P11, D00, D01, D11), acc);
            addc0(mkface(P00, P11, P10, D00, D11, D10), acc);
        }
        if (rp && cm) {
            F15 f = mkface(Pm, P00, P10, Dm, D00, D10);
            addKW(f.e[0], f.e[1], f.e[2], f.w, acc);
        }
        if (rm && cm) {
            F15 f = mkface(Pdd, Pu, P00, Ddd, Du, D00);
            addKW(f.h[0], f.h[1], f.h[2], f.w, acc);
            f = mkface(Pdd, P00, Pm, Ddd, D00, Dm);
            addKW(f.e[0], f.e[1], f.e[2], f.w, acc);
        }
        if (rm && cp) {
            F15 f = mkface(Pu, P01, P00, Du, D01, D00);
            addKW(f.h[0], f.h[1], f.h[2], f.w, acc);
        }
        s = sq_acc(acc);
    }
#pragma unroll
    for (int o = 32; o > 0; o >>= 1) s += __shfl_down(s, o, 64);
    __shared__ float sm[4];
    int lane = threadIdx.x & 63, wid = threadIdx.x >> 6;
    if (lane == 0) sm[wid] = s;
    __syncthreads();
    if (threadIdx.x == 0)
        partials[blockIdx.x] = sm[0] + sm[1] + sm[2] + sm[3];
}

__global__ void finalize_sum(const float* __restrict__ partials, int nparts,
                             float* __restrict__ out, int n)
{
    float s = 0.0f;
    for (int i = threadIdx.x; i < nparts; i += 256) s += partials[i];
#pragma unroll
    for (int o = 32; o > 0; o >>= 1) s += __shfl_down(s, o, 64);
    __shared__ float sm[4];
    int lane = threadIdx.x & 63, wid = threadIdx.x >> 6;
    if (lane == 0) sm[wid] = s;
    __syncthreads();
    if (threadIdx.x == 0)
        out[0] = (sm[0] + sm[1] + sm[2] + sm[3]) / (3.0f * (float)n);
}

// ---------------------------------------------------------------------------

extern "C" void kernel_launch(void* const* d_in, const int* in_sizes, int n_in,
                              void* d_out, int out_size, void* d_ws, size_t ws_size,
                              hipStream_t stream)
{
    const float* vs = (const float*)d_in[0];
    const float* vt = (const float*)d_in[1];
    int n = in_sizes[0] / 3;
    int F = in_sizes[2] / 3;

    int W = (int)(sqrt((double)n) + 0.5);
    int H = (W > 0) ? n / W : 0;
    bool grid_ok = (W > 1) && ((long long)W * H == n) &&
                   (2LL * (W - 1) * (H - 1) == F);

    float* partials = (float*)d_ws;

    if (grid_ok && (H % MK == 0)) {
        dim3 block(256, 1, 1);
        dim3 grid((W + BOUT - 1) / BOUT, H / MK, 1);
        int nparts = grid.x * grid.y;
        hess_face2<<<grid, block, 0, stream>>>(vs, vt, partials, W, H);
        finalize_sum<<<1, 256, 0, stream>>>(partials, nparts, (float*)d_out, n);
    } else {
        int threads = 256;
        int blocks = (n + threads - 1) / threads;
        hess_gather<<<blocks, threads, 0, stream>>>(vs, vt, partials, W, H);
        finalize_sum<<<1, 256, 0, stream>>>(partials, blocks, (float*)d_out, n);
    }
}